// Round 12
// baseline (34.920 us; speedup 1.0000x reference)
//
#include <hip/hip_runtime.h>

// MultiEmbedding: out[n,s,:] = sum_l weight[l, x[n,l,s], :]
// weight: [L=8, K=1024, D=512] f32, x: [N=8, L=8, S=4096] int32
// out: [N=8, S=4096, D=512] f32
//
// Model after rounds 2/5/6/8: gather phase is bound by vmem gather
// INSTRUCTION/request throughput (~const per wave-gather), not bytes:
// fp32 (524K inst, 536 MB) == bf16-dwordx2 (524K inst, 268 MB) == ~28-30 us.
// This round (4th resubmit after infra failures): bf16 with 16 lanes x
// dwordx4 = full 256-B slice per gather -> 262K instructions (the bf16
// minimum, half of round 2).
// Chunks: 4 x 128 floats; chunk = blockIdx&3 -> chunk pinned to 2 XCDs,
// bf16 slice 2.1 MB fits 4 MiB XCD L2. fp32 accumulate (absmax ~0.0625).

#define LVL 8
#define KTOK 1024
#define DIM 512
#define SEQ 4096
#define NB 8

typedef float f4 __attribute__((ext_vector_type(4)));

__device__ __forceinline__ unsigned f2bf_rne(float f) {
  unsigned u = __float_as_uint(f);
  u += 0x7FFFu + ((u >> 16) & 1u);   // round-to-nearest-even
  return u >> 16;
}

// pack 8 f32 -> 8 bf16 (uint4), one 16-B store per thread
__global__ __launch_bounds__(256) void convert_w_kernel(
    const float* __restrict__ w, unsigned* __restrict__ wb) {
  const int i = blockIdx.x * 256 + threadIdx.x;   // 8 floats per thread
  const float4 a = reinterpret_cast<const float4*>(w)[2 * i];
  const float4 b = reinterpret_cast<const float4*>(w)[2 * i + 1];
  uint4 h;
  h.x = f2bf_rne(a.x) | (f2bf_rne(a.y) << 16);
  h.y = f2bf_rne(a.z) | (f2bf_rne(a.w) << 16);
  h.z = f2bf_rne(b.x) | (f2bf_rne(b.y) << 16);
  h.w = f2bf_rne(b.z) | (f2bf_rne(b.w) << 16);
  reinterpret_cast<uint4*>(wb)[i] = h;
}

__global__ __launch_bounds__(256) void multi_embed_kernel(
    const int* __restrict__ x, const unsigned short* __restrict__ wb,
    float* __restrict__ out) {
  const int tid   = threadIdx.x;
  const int chunk = blockIdx.x & 3;            // 4 chunks of 128 floats
  const int rg    = blockIdx.x >> 2;           // 0..2047
  const int rloc  = tid >> 4;                  // 16 rows per block
  const int lane  = tid & 15;                  // 16-B bf16 slot (8 values)
  const int row   = rg * 16 + rloc;            // flat (n*SEQ + s)
  const int n     = row >> 12;
  const int s     = row & (SEQ - 1);
  const int dbase = chunk * 128 + lane * 8;    // this thread's 8 output floats

  const int*            xp = x + n * (LVL * SEQ) + s;
  const unsigned short* wp = wb + dbase;

  int idx[LVL];
#pragma unroll
  for (int l = 0; l < LVL; ++l) idx[l] = xp[l * SEQ];

  // one dwordx4 per (row-slice, level): 16 lanes x 16 B = full 256-B segment
  uint4 g[LVL];
#pragma unroll
  for (int l = 0; l < LVL; ++l)
    g[l] = *reinterpret_cast<const uint4*>(wp + (size_t)(l * KTOK + idx[l]) * DIM);

  float a0 = 0.f, a1 = 0.f, a2 = 0.f, a3 = 0.f;
  float a4 = 0.f, a5 = 0.f, a6 = 0.f, a7 = 0.f;
#pragma unroll
  for (int l = 0; l < LVL; ++l) {
    a0 += __uint_as_float(g[l].x << 16);
    a1 += __uint_as_float(g[l].x & 0xFFFF0000u);
    a2 += __uint_as_float(g[l].y << 16);
    a3 += __uint_as_float(g[l].y & 0xFFFF0000u);
    a4 += __uint_as_float(g[l].z << 16);
    a5 += __uint_as_float(g[l].z & 0xFFFF0000u);
    a6 += __uint_as_float(g[l].w << 16);
    a7 += __uint_as_float(g[l].w & 0xFFFF0000u);
  }

  float* o = out + (size_t)row * DIM + dbase;
  f4 lo = {a0, a1, a2, a3};
  f4 hi = {a4, a5, a6, a7};
  __builtin_nontemporal_store(lo, reinterpret_cast<f4*>(o));
  __builtin_nontemporal_store(hi, reinterpret_cast<f4*>(o) + 1);
}

extern "C" void kernel_launch(void* const* d_in, const int* in_sizes, int n_in,
                              void* d_out, int out_size, void* d_ws, size_t ws_size,
                              hipStream_t stream) {
  const int*   x = (const int*)d_in[0];    // [N, L, S]
  const float* w = (const float*)d_in[1];  // [L, K, D]
  float*     out = (float*)d_out;          // [N, S, D]
  unsigned*   wb = (unsigned*)d_ws;        // bf16 weights, 8.4 MB

  // convert f32 -> bf16: 4,194,304 floats / 8 per thread / 256 = 2048 blocks
  convert_w_kernel<<<dim3((LVL * KTOK * DIM) / 8 / 256), dim3(256), 0, stream>>>(w, wb);

  // gather-sum: (32768 rows / 16 per block) * 4 chunks = 8192 blocks
  multi_embed_kernel<<<dim3((NB * SEQ / 16) * 4), dim3(256), 0, stream>>>(
      x, (const unsigned short*)wb, out);
}

// Round 13
// 30.280 us; speedup vs baseline: 1.1532x; 1.1532x over previous
//
#include <hip/hip_runtime.h>

// MultiEmbedding: out[n,s,:] = sum_l weight[l, x[n,l,s], :]
// weight: [L=8, K=1024, D=512] f32, x: [N=8, L=8, S=4096] int32
// out: [N=8, S=4096, D=512] f32
//
// Measured invariant (rounds 2-12): gather-phase time pinned at ~27.5 us
// across fp32/bf16, 524K/262K gather instrs, 536/268 MB gather bytes, and
// store-pattern variants -- all of which used __builtin_nontemporal_store.
// New theory: the 64 MB NT store stream is the wall (~2.3 TB/s, no L2
// write-combining); gathers are L2-resident and hidden beneath it. Harness
// fill kernels sustain 6.5 TB/s with NORMAL stores.
// This round: exact round-2 structure (fastest known, exact fp32 math,
// single kernel) with PLAIN stores through L2. A/B on the store path only.

#define LVL 8
#define KTOK 1024
#define DIM 512
#define SEQ 4096
#define NB 8
#define CHUNKF 64                  // floats per D-chunk
#define NCHUNK (DIM / CHUNKF)      // 8 chunks, one per XCD

typedef float f4 __attribute__((ext_vector_type(4)));

__global__ __launch_bounds__(256) void multi_embed_kernel(
    const int* __restrict__ x, const float* __restrict__ w, float* __restrict__ out) {
  const int tid   = threadIdx.x;
  const int chunk = blockIdx.x & (NCHUNK - 1);  // XCD-pinned D-chunk
  const int rg    = blockIdx.x >> 3;            // row group, 0..2047
  const int slot  = tid & 15;                   // float4 slot within chunk
  const int rloc  = tid >> 4;                   // 16 rows per block
  const int dbase = chunk * CHUNKF + slot * 4;

  const int row = rg * 16 + rloc;               // flat (n*SEQ + s)
  const int n   = row >> 12;
  const int s   = row & (SEQ - 1);

  const int*   xp = x + n * (LVL * SEQ) + s;
  const float* wp = w + dbase;

  int idx[LVL];
#pragma unroll
  for (int l = 0; l < LVL; ++l) idx[l] = xp[l * SEQ];

  f4 acc = {0.f, 0.f, 0.f, 0.f};
#pragma unroll
  for (int l = 0; l < LVL; ++l)
    acc += *reinterpret_cast<const f4*>(wp + (size_t)(l * KTOK + idx[l]) * DIM);

  // plain store: route through L2 for write-combining (NT was the ~2.3 TB/s wall)
  *reinterpret_cast<f4*>(out + (size_t)row * DIM + dbase) = acc;
}

extern "C" void kernel_launch(void* const* d_in, const int* in_sizes, int n_in,
                              void* d_out, int out_size, void* d_ws, size_t ws_size,
                              hipStream_t stream) {
  const int*   x = (const int*)d_in[0];    // [N, L, S]
  const float* w = (const float*)d_in[1];  // [L, K, D]
  float*     out = (float*)d_out;          // [N, S, D]

  // 32768 rows / 16 per block * 8 chunks = 16384 blocks
  multi_embed_kernel<<<dim3((NB * SEQ / 16) * NCHUNK), dim3(256), 0, stream>>>(x, w, out);
}

// Round 14
// 27.673 us; speedup vs baseline: 1.2619x; 1.0942x over previous
//
#include <hip/hip_runtime.h>

// INSTRUMENTATION ROUND. R2 structure (fastest known: fp32, XCD-chunked,
// NT stores, 27.7 us) with an internal 2x repeat of the whole gather+store.
// Purpose: our kernel has been invisible in rocprof top-5 (harness fill
// kernels at ~41 us > our ~28 us). Doubling on-GPU work surfaces the
// dispatch (~55 us) WITH its FETCH_SIZE/WRITE_SIZE, discriminating:
//   FETCH ~>=200 MB  -> weight re-fetch per iteration (L2 not holding) -> fix fetch
//   FETCH ~100-130 MB -> traffic near-minimal -> efficiency/roofline regime
// asm "memory" clobber between reps prevents the compiler CSE'ing the
// second rep's loads (stores alone wouldn't force re-issue).

#define LVL 8
#define KTOK 1024
#define DIM 512
#define SEQ 4096
#define NB 8
#define CHUNKF 64                  // floats per D-chunk
#define NCHUNK (DIM / CHUNKF)      // 8 chunks, one per XCD

typedef float f4 __attribute__((ext_vector_type(4)));

__global__ __launch_bounds__(256) void multi_embed_kernel(
    const int* __restrict__ x, const float* __restrict__ w, float* __restrict__ out) {
  const int tid   = threadIdx.x;
  const int chunk = blockIdx.x & (NCHUNK - 1);  // XCD-pinned D-chunk
  const int rg    = blockIdx.x >> 3;            // row group, 0..2047
  const int slot  = tid & 15;                   // float4 slot within chunk
  const int rloc  = tid >> 4;                   // 16 rows per block
  const int dbase = chunk * CHUNKF + slot * 4;

  const int row = rg * 16 + rloc;               // flat (n*SEQ + s)
  const int n   = row >> 12;
  const int s   = row & (SEQ - 1);

  const int*   xp = x + n * (LVL * SEQ) + s;
  const float* wp = w + dbase;

  for (int rep = 0; rep < 2; ++rep) {
    int idx[LVL];
#pragma unroll
    for (int l = 0; l < LVL; ++l) idx[l] = xp[l * SEQ];

    f4 acc = {0.f, 0.f, 0.f, 0.f};
#pragma unroll
    for (int l = 0; l < LVL; ++l)
      acc += *reinterpret_cast<const f4*>(wp + (size_t)(l * KTOK + idx[l]) * DIM);

    __builtin_nontemporal_store(
        acc, reinterpret_cast<f4*>(out + (size_t)row * DIM + dbase));

    asm volatile("" ::: "memory");  // force rep 2 to re-issue all loads
  }
}

extern "C" void kernel_launch(void* const* d_in, const int* in_sizes, int n_in,
                              void* d_out, int out_size, void* d_ws, size_t ws_size,
                              hipStream_t stream) {
  const int*   x = (const int*)d_in[0];    // [N, L, S]
  const float* w = (const float*)d_in[1];  // [L, K, D]
  float*     out = (float*)d_out;          // [N, S, D]

  // 32768 rows / 16 per block * 8 chunks = 16384 blocks
  multi_embed_kernel<<<dim3((NB * SEQ / 16) * NCHUNK), dim3(256), 0, stream>>>(x, w, out);
}